// Round 1
// baseline (126.038 us; speedup 1.0000x reference)
//
#include <hip/hip_runtime.h>
#include <math.h>

#define BATCH 4096
#define NNODES 10000
#define KCAND 100

// Per-batch params: {r, x_min, y_min, any_valid}
__global__ void bbox_reduce_kernel(const float* __restrict__ nodes,
                                   const int* __restrict__ cand,
                                   float4* __restrict__ params) {
    const int wave = threadIdx.x >> 6;            // 4 waves per block
    const int lane = threadIdx.x & 63;
    const int b = blockIdx.x * 4 + wave;
    if (b >= BATCH) return;

    const int* ib = cand + (size_t)b * KCAND;
    const float* nb = nodes + (size_t)b * (size_t)NNODES * 2;

    float xmin =  INFINITY, xmax = -INFINITY;
    float ymin =  INFINITY, ymax = -INFINITY;
    bool any = false;

    for (int c = lane; c < KCAND; c += 64) {
        int id = ib[c];
        if (id != -1) {
            any = true;
            const float2 p = *reinterpret_cast<const float2*>(nb + (size_t)id * 2);
            xmin = fminf(xmin, p.x);
            xmax = fmaxf(xmax, p.x);
            ymin = fminf(ymin, p.y);
            ymax = fmaxf(ymax, p.y);
        }
    }

    // 64-lane butterfly reduction
    #pragma unroll
    for (int off = 32; off > 0; off >>= 1) {
        xmin = fminf(xmin, __shfl_xor(xmin, off, 64));
        xmax = fmaxf(xmax, __shfl_xor(xmax, off, 64));
        ymin = fminf(ymin, __shfl_xor(ymin, off, 64));
        ymax = fmaxf(ymax, __shfl_xor(ymax, off, 64));
    }
    const bool any_valid = __any(any);

    if (lane == 0) {
        float span = fmaxf(xmax - xmin, ymax - ymin);
        float r = 1.0f / fmaxf(span, 1e-6f);
        params[b] = make_float4(r, xmin, ymin, any_valid ? 1.0f : 0.0f);
    }
}

// Each batch row has NNODES*2 = 20000 floats = 5000 float4s.
#define F4_PER_BATCH (NNODES * 2 / 4)

__global__ void normalize_kernel(const float* __restrict__ nodes,
                                 const float4* __restrict__ params,
                                 float* __restrict__ out) {
    const int b = blockIdx.y;
    const int i = blockIdx.x * blockDim.x + threadIdx.x;
    if (i >= F4_PER_BATCH) return;

    const float4 p = params[b];   // broadcast, L2-cached
    const float4* src = reinterpret_cast<const float4*>(nodes + (size_t)b * (NNODES * 2));
    float4* dst = reinterpret_cast<float4*>(out + (size_t)b * (NNODES * 2));

    float4 v = src[i];
    if (p.w != 0.0f) {
        // layout: x,y,x,y — x uses x_min (p.y), y uses y_min (p.z), both scale p.x
        v.x = fminf(fmaxf(p.x * (v.x - p.y), 0.0f), 1.0f);
        v.y = fminf(fmaxf(p.x * (v.y - p.z), 0.0f), 1.0f);
        v.z = fminf(fmaxf(p.x * (v.z - p.y), 0.0f), 1.0f);
        v.w = fminf(fmaxf(p.x * (v.w - p.z), 0.0f), 1.0f);
    }
    dst[i] = v;
}

extern "C" void kernel_launch(void* const* d_in, const int* in_sizes, int n_in,
                              void* d_out, int out_size, void* d_ws, size_t ws_size,
                              hipStream_t stream) {
    const float* nodes = (const float*)d_in[0];
    const int* cand = (const int*)d_in[1];
    float* out = (float*)d_out;
    float4* params = (float4*)d_ws;   // BATCH * 16 bytes = 64 KB

    // 1) per-batch bbox reduce: 4 batches per 256-thread block
    bbox_reduce_kernel<<<dim3(BATCH / 4), dim3(256), 0, stream>>>(nodes, cand, params);

    // 2) normalize all nodes, float4-vectorized
    dim3 grid((F4_PER_BATCH + 255) / 256, BATCH);
    normalize_kernel<<<grid, dim3(256), 0, stream>>>(nodes, params, out);
}